// Round 14
// baseline (872.575 us; speedup 1.0000x reference)
//
#include <hip/hip_runtime.h>
#include <math.h>

#define B_ 32
#define SSRC 512
#define D_ 512
#define STRIDE_ 4
#define V_ 512
#define L_ 256
#define T_ (SSRC * STRIDE_)   // 2048
#define S_ (2 * L_ + 1)       // 513
#define BLANKI 1
#define PSTRIDE 264           // compact prob row stride (ushorts)
#define BOOST 4096.0f         // 2^12 pre-boost on gathered probs
#define BOOST_BITS 12
#define NCONS 64              // consumer blocks (fwd 0..31, bwd 32..63)

typedef __attribute__((ext_vector_type(8))) short bf16x8;
typedef __attribute__((ext_vector_type(4))) float f32x4;

__device__ __forceinline__ unsigned short bf16r(float x) {
    unsigned u = __float_as_uint(x);
    return (unsigned short)((u + 0x7fffu + ((u >> 16) & 1u)) >> 16);
}
__device__ __forceinline__ float bf2f(unsigned short u) {
    return __uint_as_float((unsigned)u << 16);
}
__device__ __forceinline__ void gl_lds16(const unsigned short* g, unsigned short* l) {
    __builtin_amdgcn_global_load_lds(
        (const __attribute__((address_space(1))) unsigned int*)g,
        (__attribute__((address_space(3))) unsigned int*)l, 16, 0, 0);
}

// ---------------------------------------------------------------------------
__global__ __launch_bounds__(256) void combine_bias(
    const float* __restrict__ b_exp, const float* __restrict__ W1,
    const float* __restrict__ b1, float* __restrict__ bc)
{
    int j = blockIdx.x * 256 + threadIdx.x;
    int k = j >> 10, h = j & 1023;
    float s = b1[h];
    const float* be = b_exp + k * 512;
    for (int d = 0; d < 512; ++d)
        s = fmaf(be[d], W1[d * 1024 + h], s);
    bc[j] = s;
}

// ---------------------------------------------------------------------------
__global__ __launch_bounds__(256) void transpose_cvt(
    const float* __restrict__ in, unsigned short* __restrict__ out, int R, int C)
{
    __shared__ float tile[32][33];
    int bx = blockIdx.x * 32, by = blockIdx.y * 32;
    int tx = threadIdx.x, ty = threadIdx.y;
#pragma unroll
    for (int i = 0; i < 32; i += 8)
        tile[ty + i][tx] = in[(size_t)(by + ty + i) * C + bx + tx];
    __syncthreads();
#pragma unroll
    for (int i = 0; i < 32; i += 8)
        out[(size_t)(bx + ty + i) * R + by + tx] = bf16r(tile[tx][ty + i]);
}

__global__ __launch_bounds__(256) void cvt_f32_bf16(
    const float* __restrict__ in, unsigned short* __restrict__ out, int n4)
{
    int i = blockIdx.x * 256 + threadIdx.x;
    if (i >= n4) return;
    float4 v = ((const float4*)in)[i];
    ushort4 o;
    o.x = bf16r(v.x); o.y = bf16r(v.y); o.z = bf16r(v.z); o.w = bf16r(v.w);
    ((ushort4*)out)[i] = o;
}

// ---------------------------------------------------------------------------
// bf16 MFMA GEMM (m97 structure) + bijective XCD swizzle (nwg % 8 == 0).
// ---------------------------------------------------------------------------
template <bool RELU, bool OUTBF16, bool BIAS>
__global__ __launch_bounds__(256) void gemm_mfma(
    const unsigned short* __restrict__ A, int lda, long zA,
    const unsigned short* __restrict__ BT, int ldb, long zBT,
    void* __restrict__ Cvoid, int ldc, long zC,
    const float* __restrict__ bias, int K)
{
    __shared__ unsigned short As[2][128][32];
    __shared__ unsigned short Bs[2][128][32];
    const int tid = threadIdx.x;
    const int wid = tid >> 6, lane = tid & 63;

    A  += (size_t)blockIdx.z * zA;
    BT += (size_t)blockIdx.z * zBT;
    unsigned short* Cb = OUTBF16 ? ((unsigned short*)Cvoid + (size_t)blockIdx.z * zC) : nullptr;
    float*          Cf = OUTBF16 ? nullptr : ((float*)Cvoid + (size_t)blockIdx.z * zC);

    const int gx = gridDim.x;
    int wg = blockIdx.y * gx + blockIdx.x;
    const int q = (gx * gridDim.y) >> 3;
    wg = (wg & 7) * q + (wg >> 3);
    const int bm = (wg / gx) * 128, bn = (wg % gx) * 128;

    const int wm = (wid >> 1) * 64, wn = (wid & 1) * 64;

    f32x4 acc[4][4] = {};
    const int r_in = lane >> 2;
    const int cch = (lane & 3) * 8;
    const int rbase = wid * 32;

    auto stage = [&](int buf, int k0) {
#pragma unroll
        for (int i = 0; i < 2; ++i) {
            int rloc = rbase + i * 16;
            gl_lds16(A  + (size_t)(bm + rloc + r_in) * lda + k0 + cch, &As[buf][rloc][0]);
            gl_lds16(BT + (size_t)(bn + rloc + r_in) * ldb + k0 + cch, &Bs[buf][rloc][0]);
        }
    };

    const int nt = K / 32;
    stage(0, 0);
    for (int t = 0; t < nt; ++t) {
        int cur = t & 1;
        __syncthreads();
        if (t + 1 < nt) stage(cur ^ 1, (t + 1) * 32);
        bf16x8 af[4], bfr[4];
#pragma unroll
        for (int mi = 0; mi < 4; ++mi)
            af[mi] = *(const bf16x8*)&As[cur][wm + mi * 16 + (lane & 15)][(lane >> 4) * 8];
#pragma unroll
        for (int ni = 0; ni < 4; ++ni)
            bfr[ni] = *(const bf16x8*)&Bs[cur][wn + ni * 16 + (lane & 15)][(lane >> 4) * 8];
#pragma unroll
        for (int mi = 0; mi < 4; ++mi)
#pragma unroll
            for (int ni = 0; ni < 4; ++ni)
                acc[mi][ni] = __builtin_amdgcn_mfma_f32_16x16x32_bf16(
                    af[mi], bfr[ni], acc[mi][ni], 0, 0, 0);
    }

#pragma unroll
    for (int ni = 0; ni < 4; ++ni) {
        int gcol = bn + wn + ni * 16 + (lane & 15);
        float bv = BIAS ? bias[gcol] : 0.f;
#pragma unroll
        for (int mi = 0; mi < 4; ++mi) {
#pragma unroll
            for (int q2 = 0; q2 < 4; ++q2) {
                int grow = bm + wm + mi * 16 + ((lane >> 4) << 2) + q2;
                float x = acc[mi][ni][q2] + bv;
                if (RELU) x = fmaxf(x, 0.f);
                if (OUTBF16)
                    Cb[(size_t)grow * ldc + gcol] = bf16r(x);
                else
                    Cf[(size_t)grow * ldc + gcol] = x;
            }
        }
    }
}

// ---------------------------------------------------------------------------
// Producer-consumer fused kernel.
// Blocks 0..63: CONSUMER — f64 fwd/bwd CTC DP (R12 structure, 1 wave; threads
//   >=64 exit). Spin-waits on per-chunk flags (ACQUIRE, agent scope).
// Blocks 64..575: PRODUCER — gemm2+logsoftmax+gather for one 128-row chunk
//   (R13 v4 body). Chunk order interleaved (0,15,1,14,...) per sample so fwd
//   and bwd streams both fill continuously. RELEASE flag after writes.
// Producers never wait -> no deadlock. LDS 80KB -> 2 blocks/CU; a producer
// co-resides with each consumer.
// ---------------------------------------------------------------------------
struct Pr5 { float pb, p1, p3, p5, p7; };

__device__ __forceinline__ Pr5 ldrowf(const unsigned short* rp, int l)
{
    ushort4 q = *(const ushort4*)(rp + 4 * l);
    Pr5 r;
    r.pb = bf2f(rp[256]);
    r.p1 = bf2f(q.x); r.p3 = bf2f(q.y); r.p5 = bf2f(q.z); r.p7 = bf2f(q.w);
    return r;
}

#define REP16(OP) OP(0) OP(1) OP(2) OP(3) OP(4) OP(5) OP(6) OP(7) \
                  OP(8) OP(9) OP(10) OP(11) OP(12) OP(13) OP(14) OP(15)

__global__ __launch_bounds__(1024) void gemm2_lsm_ctc(
    const unsigned short* __restrict__ H,     // [65536][1024] bf16 (= d_out)
    const unsigned short* __restrict__ W2T,   // [512][1024] bf16
    const float* __restrict__ b2,             // [512]
    const int* __restrict__ targets,          // [B][256]
    const int* __restrict__ enc_mask, const int* __restrict__ tgt_mask,
    float* __restrict__ lp,                   // [65536][512] f32 (= d_out)
    unsigned short* __restrict__ P,           // [65536][PSTRIDE]
    int* __restrict__ flags,                  // [512] chunk-ready flags
    float* __restrict__ out_len_f,
    double* __restrict__ AV, double* __restrict__ BV,
    int* __restrict__ EF, int* __restrict__ EB,
    int* __restrict__ ILv, int* __restrict__ tl_out)
{
    __shared__ __align__(16) char SMEM[81920];
    const int tid = threadIdx.x;

    if (blockIdx.x < NCONS) {
        // ===================== CONSUMER: CTC DP =====================
        if (tid >= 64) return;
        const int task = blockIdx.x;
        const int b = task & 31;
        const bool isf = task < 32;
        const int l = tid;

        int se = 0, st = 0;
        {
            const int* em = enc_mask + (size_t)b * SSRC;
#pragma unroll
            for (int i = 0; i < 8; ++i) se += (em[i * 64 + l] != 0) ? 1 : 0;
            const int* tm = tgt_mask + (size_t)b * L_;
#pragma unroll
            for (int i = 0; i < 4; ++i) st += (tm[i * 64 + l] != 0) ? 1 : 0;
#pragma unroll
            for (int off = 32; off; off >>= 1) {
                se += __shfl_xor(se, off);
                st += __shfl_xor(st, off);
            }
        }
        const int tl = st;
        const int IL = STRIDE_ * se;
        const int h = (IL > 0) ? ((IL - 1) >> 1) : 0;

        const int4 tg = ((const int4*)(targets + (size_t)b * L_))[l];
        int prevw = __shfl_up(tg.w, 1);
        if (l == 0) prevw = BLANKI;
        const bool k1 = (tg.x != BLANKI) && (tg.x != prevw);
        const bool k3 = (tg.y != BLANKI) && (tg.y != tg.x);
        const bool k5 = (tg.z != BLANKI) && (tg.z != tg.y);
        const bool k7 = (tg.w != BLANKI) && (tg.w != tg.z);

        const unsigned short* Pb = P + (size_t)b * T_ * PSTRIDE;

        double a0 = 0, a1 = 0, a2 = 0, a3 = 0, a4 = 0, a5 = 0, a6 = 0, a7 = 0, a8 = 0;
        int Ei = 0;

        auto rescale9 = [&]() {
            double m = fmax(fmax(fmax(a0, a1), fmax(a2, a3)),
                            fmax(fmax(a4, a5), fmax(fmax(a6, a7), a8)));
            int e = (int)((__double_as_longlong(m) >> 52) & 0x7ff);
#pragma unroll
            for (int off = 1; off < 64; off <<= 1) {
                int o = __shfl_xor(e, off);
                e = o > e ? o : e;
            }
            int sh = 1023 - e;
            double sc = __longlong_as_double(((long long)(sh + 1023)) << 52);
            Ei += e - 1023;
            a0 *= sc; a1 *= sc; a2 *= sc; a3 *= sc; a4 *= sc;
            a5 *= sc; a6 *= sc; a7 *= sc; a8 *= sc;
        };
        auto waitflag = [&](int c) {
            const int f = b * 16 + c;
            while (__hip_atomic_load(&flags[f], __ATOMIC_ACQUIRE,
                                     __HIP_MEMORY_SCOPE_AGENT) == 0)
                __builtin_amdgcn_s_sleep(16);
        };

        if (isf) {
            int nw = 0;
            auto waitup = [&](int row) {
                int tc = row >> 7; if (tc > 15) tc = 15;
                while (nw <= tc) { waitflag(nw); ++nw; }
            };
            waitup(0);
            if (l == 0) {
                a0 = (double)bf2f(Pb[256]);
                if (tl > 0) a1 = (double)bf2f(Pb[0]);
            }
            auto fstep = [&](const Pr5& r) {
                double pb = (double)r.pb, p1 = (double)r.p1, p3 = (double)r.p3;
                double p5 = (double)r.p5, p7 = (double)r.p7;
                double u1 = __shfl_up(a7, 1);
                if (l == 0) u1 = 0.0;
                double n0 = (a0 + u1) * pb;
                double n1 = (a0 + a1 + (k1 ? u1 : 0.0)) * p1;
                double n2 = (a1 + a2) * pb;
                double n3 = (a2 + a3 + (k3 ? a1 : 0.0)) * p3;
                double n4 = (a3 + a4) * pb;
                double n5 = (a4 + a5 + (k5 ? a3 : 0.0)) * p5;
                double n6 = (a5 + a6) * pb;
                double n7 = (a6 + a7 + (k7 ? a5 : 0.0)) * p7;
                double n8 = (l == 63) ? (a7 + a8) * pb : 0.0;
                a0 = n0; a1 = n1; a2 = n2; a3 = n3; a4 = n4;
                a5 = n5; a6 = n6; a7 = n7; a8 = n8;
            };
            const int nst = h;
            if (nst > 0) {
                waitup(nst < 47 ? nst : 47);
                Pr5 q0, q1, q2, q3, q4, q5, q6, q7, q8, q9, q10, q11, q12, q13, q14, q15;
#define LDI(i) { int ti = 1 + i; if (ti > nst) ti = nst; \
                 q##i = ldrowf(Pb + (size_t)ti * PSTRIDE, l); }
                REP16(LDI)
#undef LDI
                int t = 1;
                while (t + 15 <= nst) {
                    { int r2 = t + 47; if (r2 > nst) r2 = nst; waitup(r2); }
#define STP(i) { fstep(q##i); int ti = t + 16 + i; if (ti > nst) ti = nst; \
                 q##i = ldrowf(Pb + (size_t)ti * PSTRIDE, l); }
                    REP16(STP)
#undef STP
                    rescale9();
                    t += 16;
                }
                int rem = nst - t + 1;
#define TLS(i) if (i < rem) fstep(q##i);
                REP16(TLS)
#undef TLS
            }
            rescale9();
            double* av = AV + b * 520;
            av[l * 8 + 0] = a0; av[l * 8 + 1] = a1; av[l * 8 + 2] = a2; av[l * 8 + 3] = a3;
            av[l * 8 + 4] = a4; av[l * 8 + 5] = a5; av[l * 8 + 6] = a6; av[l * 8 + 7] = a7;
            if (l == 63) av[512] = a8;
            if (l == 0) {
                EF[b] = Ei; ILv[b] = IL; tl_out[b] = tl;
                out_len_f[b] = (float)IL;
            }
        } else {
            int nb = 15;
            auto waitdn = [&](int row) {
                int tc = row >> 7; if (tc < 0) tc = 0;
                while (nb >= tc) { waitflag(nb); --nb; }
            };
            {
                int s0 = l * 8;
                int e0 = 2 * tl, e1 = 2 * tl - 1;
                a0 = (s0 + 0 == e0 || (tl > 0 && s0 + 0 == e1)) ? 1.0 : 0.0;
                a1 = (s0 + 1 == e0 || (tl > 0 && s0 + 1 == e1)) ? 1.0 : 0.0;
                a2 = (s0 + 2 == e0 || (tl > 0 && s0 + 2 == e1)) ? 1.0 : 0.0;
                a3 = (s0 + 3 == e0 || (tl > 0 && s0 + 3 == e1)) ? 1.0 : 0.0;
                a4 = (s0 + 4 == e0 || (tl > 0 && s0 + 4 == e1)) ? 1.0 : 0.0;
                a5 = (s0 + 5 == e0 || (tl > 0 && s0 + 5 == e1)) ? 1.0 : 0.0;
                a6 = (s0 + 6 == e0 || (tl > 0 && s0 + 6 == e1)) ? 1.0 : 0.0;
                a7 = (s0 + 7 == e0 || (tl > 0 && s0 + 7 == e1)) ? 1.0 : 0.0;
                if (l == 63) a8 = (512 == e0) ? 1.0 : 0.0;
            }
            float knff = __shfl_down(k1 ? 1.f : 0.f, 1);
            if (l == 63) knff = 0.f;
            const double knf = (double)knff;
            auto bstep = [&](const Pr5& r) {
                double pb = (double)r.pb, p1 = (double)r.p1, p3 = (double)r.p3;
                double p5 = (double)r.p5, p7 = (double)r.p7;
                double g0 = a0 * pb, g1 = a1 * p1, g2 = a2 * pb, g3 = a3 * p3;
                double g4 = a4 * pb, g5 = a5 * p5, g6 = a6 * pb, g7 = a7 * p7;
                double g8 = (l == 63) ? a8 * pb : 0.0;
                double d1 = __shfl_down(g0, 1);
                double d2 = __shfl_down(g1, 1);
                if (l == 63) { d1 = g8; d2 = 0.0; }
                double m0 = g0 + g1;
                double m1 = g1 + g2 + (k3 ? g3 : 0.0);
                double m2 = g2 + g3;
                double m3 = g3 + g4 + (k5 ? g5 : 0.0);
                double m4 = g4 + g5;
                double m5 = g5 + g6 + (k7 ? g7 : 0.0);
                double m6 = g6 + g7;
                double m7 = g7 + d1 + knf * d2;
                double m8 = (l == 63) ? g8 : 0.0;
                a0 = m0; a1 = m1; a2 = m2; a3 = m3; a4 = m4;
                a5 = m5; a6 = m6; a7 = m7; a8 = m8;
            };
            const int nbs = IL - 1 - h;
            if (nbs > 0) {
                const int rmin = h + 1;
                { int r2 = IL - 1 - 47; if (r2 < rmin) r2 = rmin; waitdn(r2); }
                Pr5 q0, q1, q2, q3, q4, q5, q6, q7, q8, q9, q10, q11, q12, q13, q14, q15;
#define LDB(i) { int ri = IL - 1 - i; if (ri < rmin) ri = rmin; \
                 q##i = ldrowf(Pb + (size_t)ri * PSTRIDE, l); }
                REP16(LDB)
#undef LDB
                int j = 0;
                while (j + 16 <= nbs) {
                    { int r2 = IL - 1 - (j + 47); if (r2 < rmin) r2 = rmin; waitdn(r2); }
#define STB(i) { bstep(q##i); int ri = IL - 1 - (j + 16 + i); if (ri < rmin) ri = rmin; \
                 q##i = ldrowf(Pb + (size_t)ri * PSTRIDE, l); }
                    REP16(STB)
#undef STB
                    rescale9();
                    j += 16;
                }
                int rem = nbs - j;
#define TLB(i) if (i < rem) bstep(q##i);
                REP16(TLB)
#undef TLB
            }
            rescale9();
            double* bv = BV + b * 520;
            bv[l * 8 + 0] = a0; bv[l * 8 + 1] = a1; bv[l * 8 + 2] = a2; bv[l * 8 + 3] = a3;
            bv[l * 8 + 4] = a4; bv[l * 8 + 5] = a5; bv[l * 8 + 6] = a6; bv[l * 8 + 7] = a7;
            if (l == 63) bv[512] = a8;
            if (l == 0) EB[b] = Ei;
        }
        return;
    }

    // ===================== PRODUCER: GEMM2 + LSM + gather =====================
    unsigned short* As = (unsigned short*)SMEM;            // [2][128][32]
    unsigned short* Bs = (unsigned short*)(SMEM + 16384);  // [2][512][32]
    float* redm = (float*)SMEM;                            // [8][128] (post-loop)
    float* reds = (float*)(SMEM + 4096);                   // [8][128]
    unsigned short* prt = (unsigned short*)(SMEM + 8192);  // [64][512] bf16 prob tile
    int* s_tg = (int*)(SMEM + 8192 + 65536);               // [256]

    const int pid = blockIdx.x - NCONS;                    // 0..511
    const int smp = pid & 31;
    const int pc = pid >> 5;                               // 0..15
    const int chk = (pc & 1) ? (15 - (pc >> 1)) : (pc >> 1);
    const int r0 = smp * 2048 + chk * 128;
    const int b = smp;

    const int wid = tid >> 6, lane = tid & 63;
    const int wr = wid >> 3, wc = wid & 7;

    auto stage = [&](int buf, int k0) {
#pragma unroll
        for (int ii = 0; ii < 3; ++ii) {
            int issue = wid + 16 * ii;
            if (issue < 8) {
                int rr = issue * 16;
                gl_lds16(H + (size_t)(r0 + rr + (lane >> 2)) * 1024 + k0 + (lane & 3) * 8,
                         &As[buf * 4096 + rr * 32]);
            } else if (issue < 40) {
                int rr = (issue - 8) * 16;
                gl_lds16(W2T + (size_t)(rr + (lane >> 2)) * 1024 + k0 + (lane & 3) * 8,
                         &Bs[buf * 16384 + rr * 32]);
            }
        }
    };

    f32x4 acc[4][4] = {};
    stage(0, 0);
    for (int t = 0; t < 32; ++t) {
        const int cur = t & 1;
        __syncthreads();
        if (t + 1 < 32) stage(cur ^ 1, (t + 1) * 32);
        bf16x8 af[4], bfr[4];
#pragma unroll
        for (int mi = 0; mi < 4; ++mi)
            af[mi] = *(const bf16x8*)&As[cur * 4096 +
                        (wr * 64 + mi * 16 + (lane & 15)) * 32 + (lane >> 4) * 8];
#pragma unroll
        for (int ni = 0; ni < 4; ++ni)
            bfr[ni] = *(const bf16x8*)&Bs[cur * 16384 +
                        (wc * 64 + ni * 16 + (lane & 15)) * 32 + (lane >> 4) * 8];
#pragma unroll
        for (int mi = 0; mi < 4; ++mi)
#pragma unroll
            for (int ni = 0; ni < 4; ++ni)
                acc[mi][ni] = __builtin_amdgcn_mfma_f32_16x16x32_bf16(
                    af[mi], bfr[ni], acc[mi][ni], 0, 0, 0);
    }

    float bcol[4];
#pragma unroll
    for (int ni = 0; ni < 4; ++ni) bcol[ni] = b2[wc * 64 + ni * 16 + (lane & 15)];
#pragma unroll
    for (int mi = 0; mi < 4; ++mi)
#pragma unroll
        for (int ni = 0; ni < 4; ++ni)
#pragma unroll
            for (int q = 0; q < 4; ++q) acc[mi][ni][q] += bcol[ni];

    if (tid < 256) s_tg[tid] = targets[b * L_ + tid];
    __syncthreads();

    float rm[4][4];
#pragma unroll
    for (int mi = 0; mi < 4; ++mi)
#pragma unroll
        for (int q = 0; q < 4; ++q) {
            float m = acc[mi][0][q];
#pragma unroll
            for (int ni = 1; ni < 4; ++ni) m = fmaxf(m, acc[mi][ni][q]);
#pragma unroll
            for (int off = 1; off < 16; off <<= 1) m = fmaxf(m, __shfl_xor(m, off));
            rm[mi][q] = m;
        }
    if ((lane & 15) == 0) {
#pragma unroll
        for (int mi = 0; mi < 4; ++mi)
#pragma unroll
            for (int q = 0; q < 4; ++q)
                redm[wc * 128 + wr * 64 + mi * 16 + ((lane >> 4) << 2) + q] = rm[mi][q];
    }
    __syncthreads();
#pragma unroll
    for (int mi = 0; mi < 4; ++mi)
#pragma unroll
        for (int q = 0; q < 4; ++q) {
            int row = wr * 64 + mi * 16 + ((lane >> 4) << 2) + q;
            float m = redm[row];
#pragma unroll
            for (int g = 1; g < 8; ++g) m = fmaxf(m, redm[g * 128 + row]);
            rm[mi][q] = m;
        }
    float rs[4][4];
#pragma unroll
    for (int mi = 0; mi < 4; ++mi)
#pragma unroll
        for (int q = 0; q < 4; ++q) {
            float s = 0.f;
#pragma unroll
            for (int ni = 0; ni < 4; ++ni) s += expf(acc[mi][ni][q] - rm[mi][q]);
#pragma unroll
            for (int off = 1; off < 16; off <<= 1) s += __shfl_xor(s, off);
            rs[mi][q] = s;
        }
    if ((lane & 15) == 0) {
#pragma unroll
        for (int mi = 0; mi < 4; ++mi)
#pragma unroll
            for (int q = 0; q < 4; ++q)
                reds[wc * 128 + wr * 64 + mi * 16 + ((lane >> 4) << 2) + q] = rs[mi][q];
    }
    __syncthreads();
#pragma unroll
    for (int mi = 0; mi < 4; ++mi)
#pragma unroll
        for (int q = 0; q < 4; ++q) {
            int row = wr * 64 + mi * 16 + ((lane >> 4) << 2) + q;
            float st = reds[row];
#pragma unroll
            for (int g = 1; g < 8; ++g) st += reds[g * 128 + row];
            rm[mi][q] = rm[mi][q] + logf(st);   // lse
        }

#pragma unroll
    for (int p = 0; p < 2; ++p) {
        if (wr == p) {
#pragma unroll
            for (int mi = 0; mi < 4; ++mi)
#pragma unroll
                for (int q = 0; q < 4; ++q) {
                    int rloc = mi * 16 + ((lane >> 4) << 2) + q;
                    int row = wr * 64 + rloc;
#pragma unroll
                    for (int ni = 0; ni < 4; ++ni) {
                        int col = wc * 64 + ni * 16 + (lane & 15);
                        float lpv = acc[mi][ni][q] - rm[mi][q];
                        lp[(size_t)(r0 + row) * 512 + col] = lpv;
                        prt[rloc * 512 + col] = bf16r(expf(lpv) * BOOST);
                    }
                }
        }
        __syncthreads();
        if (tid < 514) {
            int j = tid % 257;
            int rh = tid / 257;
            int col = (j < 256) ? s_tg[j] : BLANKI;
#pragma unroll 4
            for (int r = rh * 32; r < rh * 32 + 32; ++r)
                P[(size_t)(r0 + p * 64 + r) * PSTRIDE + j] = prt[r * 512 + col];
        }
        __syncthreads();
    }

    // publish chunk
    __threadfence();
    if (tid == 0)
        __hip_atomic_store(&flags[smp * 16 + chk], 1, __ATOMIC_RELEASE,
                           __HIP_MEMORY_SCOPE_AGENT);
}

// ---------------------------------------------------------------------------
__global__ __launch_bounds__(64) void ctc_combine(
    const double* __restrict__ AV, const double* __restrict__ BV,
    const int* __restrict__ EF, const int* __restrict__ EB,
    const int* __restrict__ ILv, float* __restrict__ per_sample)
{
    const int b = blockIdx.x, l = threadIdx.x;
    const double* av = AV + b * 520;
    const double* bv = BV + b * 520;
    double s = 0.0;
#pragma unroll
    for (int i = 0; i < 8; ++i)
        s += av[l * 8 + i] * bv[l * 8 + i];
    if (l == 63) s += av[512] * bv[512];
#pragma unroll
    for (int off = 1; off < 64; off <<= 1) s += __shfl_xor(s, off);
    if (l == 0) {
        double lg = log(s) +
            (double)(EF[b] + EB[b] - BOOST_BITS * ILv[b]) * 0.6931471805599453;
        per_sample[b] = -(float)lg;
    }
}

__global__ __launch_bounds__(64) void ctc_loss_final(
    const float* __restrict__ per_sample, const int* __restrict__ tl,
    float* __restrict__ out_loss)
{
    int tid = threadIdx.x;
    float v = 0.f;
    if (tid < B_) {
        int t = tl[tid] < 1 ? 1 : tl[tid];
        v = per_sample[tid] / (float)t;
    }
#pragma unroll
    for (int off = 32; off; off >>= 1) v += __shfl_down(v, off);
    if (tid == 0) {
        float loss = v / (float)B_;
        if (isnan(loss) || isinf(loss)) loss = 0.f;
        *out_loss = loss;
    }
}

// ---------------------------------------------------------------------------
extern "C" void kernel_launch(void* const* d_in, const int* in_sizes, int n_in,
                              void* d_out, int out_size, void* d_ws, size_t ws_size,
                              hipStream_t stream)
{
    (void)in_sizes; (void)n_in; (void)out_size; (void)ws_size;

    const float* rep      = (const float*)d_in[0];
    const int*   enc_mask = (const int*)d_in[1];
    const int*   targets  = (const int*)d_in[2];
    const int*   tgt_mask = (const int*)d_in[3];
    const float* W_exp    = (const float*)d_in[4];
    const float* b_exp    = (const float*)d_in[5];
    const float* W1       = (const float*)d_in[6];
    const float* b1       = (const float*)d_in[7];
    const float* W2       = (const float*)d_in[8];
    const float* b2       = (const float*)d_in[9];

    float* out       = (float*)d_out;
    float* logprobs  = out;                          // [65536][512] f32
    float* out_len_f = out + (size_t)B_ * T_ * V_;
    float* out_loss  = out_len_f + B_;
    unsigned short* Hd = (unsigned short*)d_out;     // H bf16 [65536][1024] (same bytes)

    // ws layout (~39.1 MB):
    unsigned short* WcT = (unsigned short*)d_ws;                  // [4096][512] bf16, 4 MB
    float* bc           = (float*)(WcT + (size_t)4096 * 512);     // [4096]
    float* per_sample   = bc + 4096;                              // [64]
    int*   tl_out       = (int*)(per_sample + 64);                // [64]
    unsigned short* P   = (unsigned short*)(tl_out + 64);         // [65536][264], 34.6 MB
    double* AV          = (double*)(P + (size_t)65536 * PSTRIDE); // [32][520] f64
    double* BV          = AV + 32 * 520;                          // [32][520] f64
    int*   EF           = (int*)(BV + 32 * 520);                  // [32]
    int*   EB           = EF + 32;                                // [32]
    int*   ILv          = EB + 32;                                // [32]
    int*   flags        = ILv + 32;                               // [512]
    // aliased inside P (all dead before producers write P):
    unsigned short* repb   = P;                                   // [16384][512]
    unsigned short* W_expb = P + (size_t)16384 * 512;             // [512][2048]
    unsigned short* W1T    = W_expb + (size_t)512 * 2048;         // [1024][512]
    unsigned short* W2T    = WcT;                                 // [512][1024] (after gemm1)

    // 1) conversions
    cvt_f32_bf16<<<8192, 256, 0, stream>>>(rep, repb, (16384 * 512) / 4);
    cvt_f32_bf16<<<1024, 256, 0, stream>>>(W_exp, W_expb, (512 * 2048) / 4);
    transpose_cvt<<<dim3(32, 16), dim3(32, 8), 0, stream>>>(W1, W1T, 512, 1024);

    // 2) fold via MFMA: WcT[(k*1024+h)][e] = sum_d W1T[h][d] * W_exp[e][k*512+d]
    gemm_mfma<false, true, false><<<dim3(4, 8, 4), 256, 0, stream>>>(
        W1T, 512, 0, W_expb, 2048, 512, WcT, 512, (long)1024 * 512, nullptr, 512);
    combine_bias<<<16, 256, 0, stream>>>(b_exp, W1, b1, bc);

    // 3) GEMM1 (single launch): H = relu(rep @ Wc + bc) bf16 -> d_out
    gemm_mfma<true, true, true><<<dim3(32, 128), 256, 0, stream>>>(
        repb, 512, 0, WcT, 512, 0, Hd, 4096, 0, bc, 512);

    // 4) W2 -> W2T (into the now-dead WcT region)
    transpose_cvt<<<dim3(16, 32), dim3(32, 8), 0, stream>>>(W2, W2T, 1024, 512);

    // 5) fused producer(GEMM2+LSM+gather) / consumer(CTC DP) kernel
    hipMemsetAsync(flags, 0, 512 * sizeof(int), stream);
    gemm2_lsm_ctc<<<NCONS + 512, 1024, 0, stream>>>(
        Hd, W2T, b2, targets, enc_mask, tgt_mask, logprobs, P, flags,
        out_len_f, AV, BV, EF, EB, ILv, tl_out);

    // 6) combine + loss
    ctc_combine<<<32, 64, 0, stream>>>(AV, BV, EF, EB, ILv, per_sample);
    ctc_loss_final<<<1, 64, 0, stream>>>(per_sample, tl_out, out_loss);
}

// Round 15
// 550.078 us; speedup vs baseline: 1.5863x; 1.5863x over previous
//
#include <hip/hip_runtime.h>
#include <math.h>

#define B_ 32
#define SSRC 512
#define D_ 512
#define STRIDE_ 4
#define V_ 512
#define L_ 256
#define T_ (SSRC * STRIDE_)   // 2048
#define S_ (2 * L_ + 1)       // 513
#define BLANKI 1
#define PSTRIDE 264           // compact prob row stride (ushorts)
#define BOOST 4096.0f         // 2^12 pre-boost on gathered probs
#define BOOST_BITS 12

typedef __attribute__((ext_vector_type(8))) short bf16x8;
typedef __attribute__((ext_vector_type(4))) float f32x4;

__device__ __forceinline__ unsigned short bf16r(float x) {
    unsigned u = __float_as_uint(x);
    return (unsigned short)((u + 0x7fffu + ((u >> 16) & 1u)) >> 16);
}
__device__ __forceinline__ float bf2f(unsigned short u) {
    return __uint_as_float((unsigned)u << 16);
}
__device__ __forceinline__ void gl_lds16(const unsigned short* g, unsigned short* l) {
    __builtin_amdgcn_global_load_lds(
        (const __attribute__((address_space(1))) unsigned int*)g,
        (__attribute__((address_space(3))) unsigned int*)l, 16, 0, 0);
}

// ---------------------------------------------------------------------------
__global__ __launch_bounds__(256) void combine_bias(
    const float* __restrict__ b_exp, const float* __restrict__ W1,
    const float* __restrict__ b1, float* __restrict__ bc)
{
    int j = blockIdx.x * 256 + threadIdx.x;
    int k = j >> 10, h = j & 1023;
    float s = b1[h];
    const float* be = b_exp + k * 512;
    for (int d = 0; d < 512; ++d)
        s = fmaf(be[d], W1[d * 1024 + h], s);
    bc[j] = s;
}

// ---------------------------------------------------------------------------
__global__ __launch_bounds__(256) void transpose_cvt(
    const float* __restrict__ in, unsigned short* __restrict__ out, int R, int C)
{
    __shared__ float tile[32][33];
    int bx = blockIdx.x * 32, by = blockIdx.y * 32;
    int tx = threadIdx.x, ty = threadIdx.y;
#pragma unroll
    for (int i = 0; i < 32; i += 8)
        tile[ty + i][tx] = in[(size_t)(by + ty + i) * C + bx + tx];
    __syncthreads();
#pragma unroll
    for (int i = 0; i < 32; i += 8)
        out[(size_t)(bx + ty + i) * R + by + tx] = bf16r(tile[tx][ty + i]);
}

__global__ __launch_bounds__(256) void cvt_f32_bf16(
    const float* __restrict__ in, unsigned short* __restrict__ out, int n4)
{
    int i = blockIdx.x * 256 + threadIdx.x;
    if (i >= n4) return;
    float4 v = ((const float4*)in)[i];
    ushort4 o;
    o.x = bf16r(v.x); o.y = bf16r(v.y); o.z = bf16r(v.z); o.w = bf16r(v.w);
    ((ushort4*)out)[i] = o;
}

// ---------------------------------------------------------------------------
// bf16 MFMA GEMM (m97 structure) + bijective XCD swizzle (nwg % 8 == 0).
// ---------------------------------------------------------------------------
template <bool RELU, bool OUTBF16, bool BIAS>
__global__ __launch_bounds__(256) void gemm_mfma(
    const unsigned short* __restrict__ A, int lda, long zA,
    const unsigned short* __restrict__ BT, int ldb, long zBT,
    void* __restrict__ Cvoid, int ldc, long zC,
    const float* __restrict__ bias, int K)
{
    __shared__ unsigned short As[2][128][32];
    __shared__ unsigned short Bs[2][128][32];
    const int tid = threadIdx.x;
    const int wid = tid >> 6, lane = tid & 63;

    A  += (size_t)blockIdx.z * zA;
    BT += (size_t)blockIdx.z * zBT;
    unsigned short* Cb = OUTBF16 ? ((unsigned short*)Cvoid + (size_t)blockIdx.z * zC) : nullptr;
    float*          Cf = OUTBF16 ? nullptr : ((float*)Cvoid + (size_t)blockIdx.z * zC);

    const int gx = gridDim.x;
    int wg = blockIdx.y * gx + blockIdx.x;
    const int q = (gx * gridDim.y) >> 3;
    wg = (wg & 7) * q + (wg >> 3);
    const int bm = (wg / gx) * 128, bn = (wg % gx) * 128;

    const int wm = (wid >> 1) * 64, wn = (wid & 1) * 64;

    f32x4 acc[4][4] = {};
    const int r_in = lane >> 2;
    const int cch = (lane & 3) * 8;
    const int rbase = wid * 32;

    auto stage = [&](int buf, int k0) {
#pragma unroll
        for (int i = 0; i < 2; ++i) {
            int rloc = rbase + i * 16;
            gl_lds16(A  + (size_t)(bm + rloc + r_in) * lda + k0 + cch, &As[buf][rloc][0]);
            gl_lds16(BT + (size_t)(bn + rloc + r_in) * ldb + k0 + cch, &Bs[buf][rloc][0]);
        }
    };

    const int nt = K / 32;
    stage(0, 0);
    for (int t = 0; t < nt; ++t) {
        int cur = t & 1;
        __syncthreads();
        if (t + 1 < nt) stage(cur ^ 1, (t + 1) * 32);
        bf16x8 af[4], bfr[4];
#pragma unroll
        for (int mi = 0; mi < 4; ++mi)
            af[mi] = *(const bf16x8*)&As[cur][wm + mi * 16 + (lane & 15)][(lane >> 4) * 8];
#pragma unroll
        for (int ni = 0; ni < 4; ++ni)
            bfr[ni] = *(const bf16x8*)&Bs[cur][wn + ni * 16 + (lane & 15)][(lane >> 4) * 8];
#pragma unroll
        for (int mi = 0; mi < 4; ++mi)
#pragma unroll
            for (int ni = 0; ni < 4; ++ni)
                acc[mi][ni] = __builtin_amdgcn_mfma_f32_16x16x32_bf16(
                    af[mi], bfr[ni], acc[mi][ni], 0, 0, 0);
    }

#pragma unroll
    for (int ni = 0; ni < 4; ++ni) {
        int gcol = bn + wn + ni * 16 + (lane & 15);
        float bv = BIAS ? bias[gcol] : 0.f;
#pragma unroll
        for (int mi = 0; mi < 4; ++mi) {
#pragma unroll
            for (int q2 = 0; q2 < 4; ++q2) {
                int grow = bm + wm + mi * 16 + ((lane >> 4) << 2) + q2;
                float x = acc[mi][ni][q2] + bv;
                if (RELU) x = fmaxf(x, 0.f);
                if (OUTBF16)
                    Cb[(size_t)grow * ldc + gcol] = bf16r(x);
                else
                    Cf[(size_t)grow * ldc + gcol] = x;
            }
        }
    }
}

// ---------------------------------------------------------------------------
// Fused GEMM2 + log_softmax + P-gather (R13 v4, verified). One block = 128
// rows x V=512; 16 waves = 2 row-groups x 8 col-groups; LDS 80KB; post-loop
// region reused for reductions + 64-row prob tile (2-phase gather into P).
// lp written IN PLACE over H (block-self-contained rows).
// ---------------------------------------------------------------------------
__global__ __launch_bounds__(1024) void gemm2_lsm(
    const unsigned short* __restrict__ H,     // [65536][1024] bf16 (= d_out)
    const unsigned short* __restrict__ W2T,   // [512][1024] bf16
    const float* __restrict__ b2,             // [512]
    const int* __restrict__ targets,          // [B][256]
    float* __restrict__ lp,                   // [65536][512] f32 (= d_out)
    unsigned short* __restrict__ P)           // [65536][PSTRIDE]
{
    __shared__ __align__(16) char SMEM[81920];
    unsigned short* As = (unsigned short*)SMEM;            // [2][128][32]
    unsigned short* Bs = (unsigned short*)(SMEM + 16384);  // [2][512][32]
    float* redm = (float*)SMEM;                            // [8][128] (post-loop)
    float* reds = (float*)(SMEM + 4096);                   // [8][128]
    unsigned short* prt = (unsigned short*)(SMEM + 8192);  // [64][512] bf16 prob tile
    int* s_tg = (int*)(SMEM + 8192 + 65536);               // [256]

    const int tid = threadIdx.x;
    const int wid = tid >> 6, lane = tid & 63;
    const int wr = wid >> 3, wc = wid & 7;
    const int r0 = blockIdx.x * 128;
    const int b = r0 >> 11;

    auto stage = [&](int buf, int k0) {
#pragma unroll
        for (int ii = 0; ii < 3; ++ii) {
            int issue = wid + 16 * ii;
            if (issue < 8) {
                int rr = issue * 16;
                gl_lds16(H + (size_t)(r0 + rr + (lane >> 2)) * 1024 + k0 + (lane & 3) * 8,
                         &As[buf * 4096 + rr * 32]);
            } else if (issue < 40) {
                int rr = (issue - 8) * 16;
                gl_lds16(W2T + (size_t)(rr + (lane >> 2)) * 1024 + k0 + (lane & 3) * 8,
                         &Bs[buf * 16384 + rr * 32]);
            }
        }
    };

    f32x4 acc[4][4] = {};
    stage(0, 0);
    for (int t = 0; t < 32; ++t) {
        const int cur = t & 1;
        __syncthreads();
        if (t + 1 < 32) stage(cur ^ 1, (t + 1) * 32);
        bf16x8 af[4], bfr[4];
#pragma unroll
        for (int mi = 0; mi < 4; ++mi)
            af[mi] = *(const bf16x8*)&As[cur * 4096 +
                        (wr * 64 + mi * 16 + (lane & 15)) * 32 + (lane >> 4) * 8];
#pragma unroll
        for (int ni = 0; ni < 4; ++ni)
            bfr[ni] = *(const bf16x8*)&Bs[cur * 16384 +
                        (wc * 64 + ni * 16 + (lane & 15)) * 32 + (lane >> 4) * 8];
#pragma unroll
        for (int mi = 0; mi < 4; ++mi)
#pragma unroll
            for (int ni = 0; ni < 4; ++ni)
                acc[mi][ni] = __builtin_amdgcn_mfma_f32_16x16x32_bf16(
                    af[mi], bfr[ni], acc[mi][ni], 0, 0, 0);
    }

    float bcol[4];
#pragma unroll
    for (int ni = 0; ni < 4; ++ni) bcol[ni] = b2[wc * 64 + ni * 16 + (lane & 15)];
#pragma unroll
    for (int mi = 0; mi < 4; ++mi)
#pragma unroll
        for (int ni = 0; ni < 4; ++ni)
#pragma unroll
            for (int q = 0; q < 4; ++q) acc[mi][ni][q] += bcol[ni];

    if (tid < 256) s_tg[tid] = targets[b * L_ + tid];
    __syncthreads();

    float rm[4][4];
#pragma unroll
    for (int mi = 0; mi < 4; ++mi)
#pragma unroll
        for (int q = 0; q < 4; ++q) {
            float m = acc[mi][0][q];
#pragma unroll
            for (int ni = 1; ni < 4; ++ni) m = fmaxf(m, acc[mi][ni][q]);
#pragma unroll
            for (int off = 1; off < 16; off <<= 1) m = fmaxf(m, __shfl_xor(m, off));
            rm[mi][q] = m;
        }
    if ((lane & 15) == 0) {
#pragma unroll
        for (int mi = 0; mi < 4; ++mi)
#pragma unroll
            for (int q = 0; q < 4; ++q)
                redm[wc * 128 + wr * 64 + mi * 16 + ((lane >> 4) << 2) + q] = rm[mi][q];
    }
    __syncthreads();
#pragma unroll
    for (int mi = 0; mi < 4; ++mi)
#pragma unroll
        for (int q = 0; q < 4; ++q) {
            int row = wr * 64 + mi * 16 + ((lane >> 4) << 2) + q;
            float m = redm[row];
#pragma unroll
            for (int g = 1; g < 8; ++g) m = fmaxf(m, redm[g * 128 + row]);
            rm[mi][q] = m;
        }
    float rs[4][4];
#pragma unroll
    for (int mi = 0; mi < 4; ++mi)
#pragma unroll
        for (int q = 0; q < 4; ++q) {
            float s = 0.f;
#pragma unroll
            for (int ni = 0; ni < 4; ++ni) s += expf(acc[mi][ni][q] - rm[mi][q]);
#pragma unroll
            for (int off = 1; off < 16; off <<= 1) s += __shfl_xor(s, off);
            rs[mi][q] = s;
        }
    if ((lane & 15) == 0) {
#pragma unroll
        for (int mi = 0; mi < 4; ++mi)
#pragma unroll
            for (int q = 0; q < 4; ++q)
                reds[wc * 128 + wr * 64 + mi * 16 + ((lane >> 4) << 2) + q] = rs[mi][q];
    }
    __syncthreads();
#pragma unroll
    for (int mi = 0; mi < 4; ++mi)
#pragma unroll
        for (int q = 0; q < 4; ++q) {
            int row = wr * 64 + mi * 16 + ((lane >> 4) << 2) + q;
            float st = reds[row];
#pragma unroll
            for (int g = 1; g < 8; ++g) st += reds[g * 128 + row];
            rm[mi][q] = rm[mi][q] + logf(st);   // lse
        }

#pragma unroll
    for (int p = 0; p < 2; ++p) {
        if (wr == p) {
#pragma unroll
            for (int mi = 0; mi < 4; ++mi)
#pragma unroll
                for (int q = 0; q < 4; ++q) {
                    int rloc = mi * 16 + ((lane >> 4) << 2) + q;
                    int row = wr * 64 + rloc;
#pragma unroll
                    for (int ni = 0; ni < 4; ++ni) {
                        int col = wc * 64 + ni * 16 + (lane & 15);
                        float lpv = acc[mi][ni][q] - rm[mi][q];
                        lp[(size_t)(r0 + row) * 512 + col] = lpv;
                        prt[rloc * 512 + col] = bf16r(expf(lpv) * BOOST);
                    }
                }
        }
        __syncthreads();
        if (tid < 514) {
            int j = tid % 257;
            int rh = tid / 257;
            int col = (j < 256) ? s_tg[j] : BLANKI;
#pragma unroll 4
            for (int r = rh * 32; r < rh * 32 + 32; ++r)
                P[(size_t)(r0 + p * 64 + r) * PSTRIDE + j] = prt[r * 512 + col];
        }
        __syncthreads();
    }
}

// ---------------------------------------------------------------------------
// CTC DP: fwd+bwd of the SAME sample interleaved in ONE wave (32 blocks x 64
// threads). The two chains are independent -> in-wave ILP fills the ~66%
// dependency-latency stalls measured in R12/R13 (cross-wave packing regressed:
// shared-CU contention). f64 accumulators, depth-8 named prefetch per stream,
// rescale every 8 steps (growth <= 2^109). Lane l owns states 8l..8l+7.
// ---------------------------------------------------------------------------
struct Pr5 { float pb, p1, p3, p5, p7; };

__device__ __forceinline__ Pr5 ldrowf(const unsigned short* rp, int l)
{
    ushort4 q = *(const ushort4*)(rp + 4 * l);
    Pr5 r;
    r.pb = bf2f(rp[256]);
    r.p1 = bf2f(q.x); r.p3 = bf2f(q.y); r.p5 = bf2f(q.z); r.p7 = bf2f(q.w);
    return r;
}

#define REP8(OP) OP(0) OP(1) OP(2) OP(3) OP(4) OP(5) OP(6) OP(7)

__global__ __launch_bounds__(64) void ctc_fb2(
    const unsigned short* __restrict__ P,
    const int* __restrict__ enc_mask, const int* __restrict__ targets,
    const int* __restrict__ tgt_mask,
    float* __restrict__ out_len_f,
    double* __restrict__ AV, double* __restrict__ BV,
    int* __restrict__ EF, int* __restrict__ EB,
    int* __restrict__ ILv, int* __restrict__ tl_out)
{
    const int b = blockIdx.x;
    const int l = threadIdx.x;

    int se = 0, st = 0;
    {
        const int* em = enc_mask + (size_t)b * SSRC;
#pragma unroll
        for (int i = 0; i < 8; ++i) se += (em[i * 64 + l] != 0) ? 1 : 0;
        const int* tm = tgt_mask + (size_t)b * L_;
#pragma unroll
        for (int i = 0; i < 4; ++i) st += (tm[i * 64 + l] != 0) ? 1 : 0;
#pragma unroll
        for (int off = 32; off; off >>= 1) {
            se += __shfl_xor(se, off);
            st += __shfl_xor(st, off);
        }
    }
    const int tl = st;
    const int IL = STRIDE_ * se;
    const int h = (IL > 0) ? ((IL - 1) >> 1) : 0;

    const int4 tg = ((const int4*)(targets + (size_t)b * L_))[l];
    int prevw = __shfl_up(tg.w, 1);
    if (l == 0) prevw = BLANKI;
    const bool k1 = (tg.x != BLANKI) && (tg.x != prevw);
    const bool k3 = (tg.y != BLANKI) && (tg.y != tg.x);
    const bool k5 = (tg.z != BLANKI) && (tg.z != tg.y);
    const bool k7 = (tg.w != BLANKI) && (tg.w != tg.z);
    float knff = __shfl_down(k1 ? 1.f : 0.f, 1);
    if (l == 63) knff = 0.f;
    const double knf = (double)knff;

    const unsigned short* Pb = P + (size_t)b * T_ * PSTRIDE;

    // forward state
    double f0 = 0, f1 = 0, f2 = 0, f3 = 0, f4 = 0, f5 = 0, f6 = 0, f7 = 0, f8 = 0;
    int EiF = 0;
    // backward state
    double g0a = 0, g1a = 0, g2a = 0, g3a = 0, g4a = 0, g5a = 0, g6a = 0, g7a = 0, g8a = 0;
    int EiB = 0;

    if (l == 0) {
        f0 = (double)bf2f(Pb[256]);
        if (tl > 0) f1 = (double)bf2f(Pb[0]);
    }
    {
        int s0 = l * 8;
        int e0 = 2 * tl, e1 = 2 * tl - 1;
        g0a = (s0 + 0 == e0 || (tl > 0 && s0 + 0 == e1)) ? 1.0 : 0.0;
        g1a = (s0 + 1 == e0 || (tl > 0 && s0 + 1 == e1)) ? 1.0 : 0.0;
        g2a = (s0 + 2 == e0 || (tl > 0 && s0 + 2 == e1)) ? 1.0 : 0.0;
        g3a = (s0 + 3 == e0 || (tl > 0 && s0 + 3 == e1)) ? 1.0 : 0.0;
        g4a = (s0 + 4 == e0 || (tl > 0 && s0 + 4 == e1)) ? 1.0 : 0.0;
        g5a = (s0 + 5 == e0 || (tl > 0 && s0 + 5 == e1)) ? 1.0 : 0.0;
        g6a = (s0 + 6 == e0 || (tl > 0 && s0 + 6 == e1)) ? 1.0 : 0.0;
        g7a = (s0 + 7 == e0 || (tl > 0 && s0 + 7 == e1)) ? 1.0 : 0.0;
        if (l == 63) g8a = (512 == e0) ? 1.0 : 0.0;
    }

    auto fstep = [&](const Pr5& r) {
        double pb = (double)r.pb, p1 = (double)r.p1, p3 = (double)r.p3;
        double p5 = (double)r.p5, p7 = (double)r.p7;
        double u1 = __shfl_up(f7, 1);
        if (l == 0) u1 = 0.0;
        double n0 = (f0 + u1) * pb;
        double n1 = (f0 + f1 + (k1 ? u1 : 0.0)) * p1;
        double n2 = (f1 + f2) * pb;
        double n3 = (f2 + f3 + (k3 ? f1 : 0.0)) * p3;
        double n4 = (f3 + f4) * pb;
        double n5 = (f4 + f5 + (k5 ? f3 : 0.0)) * p5;
        double n6 = (f5 + f6) * pb;
        double n7 = (f6 + f7 + (k7 ? f5 : 0.0)) * p7;
        double n8 = (l == 63) ? (f7 + f8) * pb : 0.0;
        f0 = n0; f1 = n1; f2 = n2; f3 = n3; f4 = n4;
        f5 = n5; f6 = n6; f7 = n7; f8 = n8;
    };
    auto bstep = [&](const Pr5& r) {
        double pb = (double)r.pb, p1 = (double)r.p1, p3 = (double)r.p3;
        double p5 = (double)r.p5, p7 = (double)r.p7;
        double g0 = g0a * pb, g1 = g1a * p1, g2 = g2a * pb, g3 = g3a * p3;
        double g4 = g4a * pb, g5 = g5a * p5, g6 = g6a * pb, g7 = g7a * p7;
        double g8 = (l == 63) ? g8a * pb : 0.0;
        double d1 = __shfl_down(g0, 1);
        double d2 = __shfl_down(g1, 1);
        if (l == 63) { d1 = g8; d2 = 0.0; }
        double m0 = g0 + g1;
        double m1 = g1 + g2 + (k3 ? g3 : 0.0);
        double m2 = g2 + g3;
        double m3 = g3 + g4 + (k5 ? g5 : 0.0);
        double m4 = g4 + g5;
        double m5 = g5 + g6 + (k7 ? g7 : 0.0);
        double m6 = g6 + g7;
        double m7 = g7 + d1 + knf * d2;
        double m8 = (l == 63) ? g8 : 0.0;
        g0a = m0; g1a = m1; g2a = m2; g3a = m3; g4a = m4;
        g5a = m5; g6a = m6; g7a = m7; g8a = m8;
    };
    auto rescaleF = [&]() {
        double m = fmax(fmax(fmax(f0, f1), fmax(f2, f3)),
                        fmax(fmax(f4, f5), fmax(fmax(f6, f7), f8)));
        int e = (int)((__double_as_longlong(m) >> 52) & 0x7ff);
#pragma unroll
        for (int off = 1; off < 64; off <<= 1) {
            int o = __shfl_xor(e, off);
            e = o > e ? o : e;
        }
        double sc = __longlong_as_double(((long long)(2046 - e)) << 52);
        EiF += e - 1023;
        f0 *= sc; f1 *= sc; f2 *= sc; f3 *= sc; f4 *= sc;
        f5 *= sc; f6 *= sc; f7 *= sc; f8 *= sc;
    };
    auto rescaleB = [&]() {
        double m = fmax(fmax(fmax(g0a, g1a), fmax(g2a, g3a)),
                        fmax(fmax(g4a, g5a), fmax(fmax(g6a, g7a), g8a)));
        int e = (int)((__double_as_longlong(m) >> 52) & 0x7ff);
#pragma unroll
        for (int off = 1; off < 64; off <<= 1) {
            int o = __shfl_xor(e, off);
            e = o > e ? o : e;
        }
        double sc = __longlong_as_double(((long long)(2046 - e)) << 52);
        EiB += e - 1023;
        g0a *= sc; g1a *= sc; g2a *= sc; g3a *= sc; g4a *= sc;
        g5a *= sc; g6a *= sc; g7a *= sc; g8a *= sc;
    };

    const int nf = h;                       // fwd steps: rows 1..h
    const int nb = IL - 1 - h;              // bwd steps: rows IL-1 .. h+1
    const int rmin = h + 1;

    if (nf > 0 || nb > 0) {
        Pr5 qf0, qf1, qf2, qf3, qf4, qf5, qf6, qf7;
        Pr5 qb0, qb1, qb2, qb3, qb4, qb5, qb6, qb7;
#define LDF(i) { int ti = 1 + i; if (ti > nf) ti = nf > 0 ? nf : 1; \
                 qf##i = ldrowf(Pb + (size_t)ti * PSTRIDE, l); }
#define LDBW(i) { int ri = IL - 1 - i; if (ri < rmin) ri = rmin; if (ri < 0) ri = 0; \
                 qb##i = ldrowf(Pb + (size_t)ri * PSTRIDE, l); }
        REP8(LDF)
        REP8(LDBW)
#undef LDF
#undef LDBW
        int t = 1, j = 0;
        // paired main loop (nf and nb differ by <= 1)
        while (t + 7 <= nf && j + 7 <= nb) {
#define PSTEP(i) { \
            fstep(qf##i); \
            { int ti = t + 8 + i; if (ti > nf) ti = nf; \
              qf##i = ldrowf(Pb + (size_t)ti * PSTRIDE, l); } \
            bstep(qb##i); \
            { int ri = IL - 1 - (j + 8 + i); if (ri < rmin) ri = rmin; \
              qb##i = ldrowf(Pb + (size_t)ri * PSTRIDE, l); } }
            REP8(PSTEP)
#undef PSTEP
            rescaleF();
            rescaleB();
            t += 8; j += 8;
        }
        // tails (each <= 8 steps, slots already hold the right rows)
        int remf = nf - t + 1; if (remf < 0) remf = 0;
        int remb = nb - j;     if (remb < 0) remb = 0;
#define TLF(i) if (i < remf) fstep(qf##i);
        REP8(TLF)
#undef TLF
#define TLB(i) if (i < remb) bstep(qb##i);
        REP8(TLB)
#undef TLB
    }
    rescaleF();
    rescaleB();

    double* av = AV + b * 520;
    av[l * 8 + 0] = f0; av[l * 8 + 1] = f1; av[l * 8 + 2] = f2; av[l * 8 + 3] = f3;
    av[l * 8 + 4] = f4; av[l * 8 + 5] = f5; av[l * 8 + 6] = f6; av[l * 8 + 7] = f7;
    if (l == 63) av[512] = f8;
    double* bv = BV + b * 520;
    bv[l * 8 + 0] = g0a; bv[l * 8 + 1] = g1a; bv[l * 8 + 2] = g2a; bv[l * 8 + 3] = g3a;
    bv[l * 8 + 4] = g4a; bv[l * 8 + 5] = g5a; bv[l * 8 + 6] = g6a; bv[l * 8 + 7] = g7a;
    if (l == 63) bv[512] = g8a;
    if (l == 0) {
        EF[b] = EiF; EB[b] = EiB; ILv[b] = IL; tl_out[b] = tl;
        out_len_f[b] = (float)IL;
    }
}

// ---------------------------------------------------------------------------
__global__ __launch_bounds__(64) void ctc_combine(
    const double* __restrict__ AV, const double* __restrict__ BV,
    const int* __restrict__ EF, const int* __restrict__ EB,
    const int* __restrict__ ILv, float* __restrict__ per_sample)
{
    const int b = blockIdx.x, l = threadIdx.x;
    const double* av = AV + b * 520;
    const double* bv = BV + b * 520;
    double s = 0.0;
#pragma unroll
    for (int i = 0; i < 8; ++i)
        s += av[l * 8 + i] * bv[l * 8 + i];
    if (l == 63) s += av[512] * bv[512];
#pragma unroll
    for (int off = 1; off < 64; off <<= 1) s += __shfl_xor(s, off);
    if (l == 0) {
        double lg = log(s) +
            (double)(EF[b] + EB[b] - BOOST_BITS * ILv[b]) * 0.6931471805599453;
        per_sample[b] = -(float)lg;
    }
}

__global__ __launch_bounds__(64) void ctc_loss_final(
    const float* __restrict__ per_sample, const int* __restrict__ tl,
    float* __restrict__ out_loss)
{
    int tid = threadIdx.x;
    float v = 0.f;
    if (tid < B_) {
        int t = tl[tid] < 1 ? 1 : tl[tid];
        v = per_sample[tid] / (float)t;
    }
#pragma unroll
    for (int off = 32; off; off >>= 1) v += __shfl_down(v, off);
    if (tid == 0) {
        float loss = v / (float)B_;
        if (isnan(loss) || isinf(loss)) loss = 0.f;
        *out_loss = loss;
    }
}

// ---------------------------------------------------------------------------
extern "C" void kernel_launch(void* const* d_in, const int* in_sizes, int n_in,
                              void* d_out, int out_size, void* d_ws, size_t ws_size,
                              hipStream_t stream)
{
    (void)in_sizes; (void)n_in; (void)out_size; (void)ws_size;

    const float* rep      = (const float*)d_in[0];
    const int*   enc_mask = (const int*)d_in[1];
    const int*   targets  = (const int*)d_in[2];
    const int*   tgt_mask = (const int*)d_in[3];
    const float* W_exp    = (const float*)d_in[4];
    const float* b_exp    = (const float*)d_in[5];
    const float* W1       = (const float*)d_in[6];
    const float* b1       = (const float*)d_in[7];
    const float* W2       = (const float*)d_in[8];
    const float* b2       = (const float*)d_in[9];

    float* out       = (float*)d_out;
    float* logprobs  = out;                          // [65536][512] f32
    float* out_len_f = out + (size_t)B_ * T_ * V_;
    float* out_loss  = out_len_f + B_;
    unsigned short* Hd = (unsigned short*)d_out;     // H bf16 [65536][1024] (same bytes)

    // ws layout (~39.1 MB):
    unsigned short* WcT = (unsigned short*)d_ws;                  // [4096][512] bf16, 4 MB
    float* bc           = (float*)(WcT + (size_t)4096 * 512);     // [4096]
    float* per_sample   = bc + 4096;                              // [64]
    int*   tl_out       = (int*)(per_sample + 64);                // [64]
    unsigned short* P   = (unsigned short*)(tl_out + 64);         // [65536][264], 34.6 MB
    double* AV          = (double*)(P + (size_t)65536 * PSTRIDE); // [32][520] f64
    double* BV          = AV + 32 * 520;                          // [32][520] f64
    int*   EF           = (int*)(BV + 32 * 520);                  // [32]
    int*   EB           = EF + 32;                                // [32]
    int*   ILv          = EB + 32;                                // [32]
    // aliased inside P (all dead before gemm2_lsm writes P):
    unsigned short* repb   = P;                                   // [16384][512]
    unsigned short* W_expb = P + (size_t)16384 * 512;             // [512][2048]
    unsigned short* W1T    = W_expb + (size_t)512 * 2048;         // [1024][512]
    unsigned short* W2T    = WcT;                                 // [512][1024] (after gemm1)

    // 1) conversions
    cvt_f32_bf16<<<8192, 256, 0, stream>>>(rep, repb, (16384 * 512) / 4);
    cvt_f32_bf16<<<1024, 256, 0, stream>>>(W_exp, W_expb, (512 * 2048) / 4);
    transpose_cvt<<<dim3(32, 16), dim3(32, 8), 0, stream>>>(W1, W1T, 512, 1024);

    // 2) fold via MFMA: WcT[(k*1024+h)][e] = sum_d W1T[h][d] * W_exp[e][k*512+d]
    gemm_mfma<false, true, false><<<dim3(4, 8, 4), 256, 0, stream>>>(
        W1T, 512, 0, W_expb, 2048, 512, WcT, 512, (long)1024 * 512, nullptr, 512);
    combine_bias<<<16, 256, 0, stream>>>(b_exp, W1, b1, bc);

    // 3) GEMM1 (single launch): H = relu(rep @ Wc + bc) bf16 -> d_out
    gemm_mfma<true, true, true><<<dim3(32, 128), 256, 0, stream>>>(
        repb, 512, 0, WcT, 512, 0, Hd, 4096, 0, bc, 512);

    // 4) W2 -> W2T (into the now-dead WcT region)
    transpose_cvt<<<dim3(16, 32), dim3(32, 8), 0, stream>>>(W2, W2T, 1024, 512);

    // 5) fused GEMM2 + log_softmax + gather (in-place lp over H; writes P)
    gemm2_lsm<<<512, 1024, 0, stream>>>(Hd, W2T, b2, targets, logprobs, P);

    // 6) CTC DP: fwd+bwd interleaved per wave (32 blocks), combine, loss
    ctc_fb2<<<B_, 64, 0, stream>>>(P, enc_mask, targets, tgt_mask,
                                   out_len_f, AV, BV, EF, EB, ILv, tl_out);
    ctc_combine<<<32, 64, 0, stream>>>(AV, BV, EF, EB, ILv, per_sample);
    ctc_loss_final<<<1, 64, 0, stream>>>(per_sample, tl_out, out_loss);
}

// Round 16
// 416.390 us; speedup vs baseline: 2.0956x; 1.3211x over previous
//
#include <hip/hip_runtime.h>
#include <math.h>

#define B_ 32
#define SSRC 512
#define D_ 512
#define STRIDE_ 4
#define V_ 512
#define L_ 256
#define T_ (SSRC * STRIDE_)   // 2048
#define S_ (2 * L_ + 1)       // 513
#define BLANKI 1
#define PSTRIDE 264           // compact prob row stride (ushorts)
#define BOOST 4096.0f         // 2^12 pre-boost on gathered probs
#define BOOST_BITS 12

typedef __attribute__((ext_vector_type(8))) short bf16x8;
typedef __attribute__((ext_vector_type(4))) float f32x4;

__device__ __forceinline__ unsigned short bf16r(float x) {
    unsigned u = __float_as_uint(x);
    return (unsigned short)((u + 0x7fffu + ((u >> 16) & 1u)) >> 16);
}
__device__ __forceinline__ float bf2f(unsigned short u) {
    return __uint_as_float((unsigned)u << 16);
}
__device__ __forceinline__ void gl_lds16(const unsigned short* g, unsigned short* l) {
    __builtin_amdgcn_global_load_lds(
        (const __attribute__((address_space(1))) unsigned int*)g,
        (__attribute__((address_space(3))) unsigned int*)l, 16, 0, 0);
}

// ---------------------------------------------------------------------------
__global__ __launch_bounds__(256) void combine_bias(
    const float* __restrict__ b_exp, const float* __restrict__ W1,
    const float* __restrict__ b1, float* __restrict__ bc)
{
    int j = blockIdx.x * 256 + threadIdx.x;
    int k = j >> 10, h = j & 1023;
    float s = b1[h];
    const float* be = b_exp + k * 512;
    for (int d = 0; d < 512; ++d)
        s = fmaf(be[d], W1[d * 1024 + h], s);
    bc[j] = s;
}

// ---------------------------------------------------------------------------
__global__ __launch_bounds__(256) void transpose_cvt(
    const float* __restrict__ in, unsigned short* __restrict__ out, int R, int C)
{
    __shared__ float tile[32][33];
    int bx = blockIdx.x * 32, by = blockIdx.y * 32;
    int tx = threadIdx.x, ty = threadIdx.y;
#pragma unroll
    for (int i = 0; i < 32; i += 8)
        tile[ty + i][tx] = in[(size_t)(by + ty + i) * C + bx + tx];
    __syncthreads();
#pragma unroll
    for (int i = 0; i < 32; i += 8)
        out[(size_t)(bx + ty + i) * R + by + tx] = bf16r(tile[tx][ty + i]);
}

__global__ __launch_bounds__(256) void cvt_f32_bf16(
    const float* __restrict__ in, unsigned short* __restrict__ out, int n4)
{
    int i = blockIdx.x * 256 + threadIdx.x;
    if (i >= n4) return;
    float4 v = ((const float4*)in)[i];
    ushort4 o;
    o.x = bf16r(v.x); o.y = bf16r(v.y); o.z = bf16r(v.z); o.w = bf16r(v.w);
    ((ushort4*)out)[i] = o;
}

// ---------------------------------------------------------------------------
// bf16 MFMA GEMM (m97 structure) + bijective XCD swizzle (nwg % 8 == 0).
// ---------------------------------------------------------------------------
template <bool RELU, bool OUTBF16, bool BIAS>
__global__ __launch_bounds__(256) void gemm_mfma(
    const unsigned short* __restrict__ A, int lda, long zA,
    const unsigned short* __restrict__ BT, int ldb, long zBT,
    void* __restrict__ Cvoid, int ldc, long zC,
    const float* __restrict__ bias, int K)
{
    __shared__ unsigned short As[2][128][32];
    __shared__ unsigned short Bs[2][128][32];
    const int tid = threadIdx.x;
    const int wid = tid >> 6, lane = tid & 63;

    A  += (size_t)blockIdx.z * zA;
    BT += (size_t)blockIdx.z * zBT;
    unsigned short* Cb = OUTBF16 ? ((unsigned short*)Cvoid + (size_t)blockIdx.z * zC) : nullptr;
    float*          Cf = OUTBF16 ? nullptr : ((float*)Cvoid + (size_t)blockIdx.z * zC);

    const int gx = gridDim.x;
    int wg = blockIdx.y * gx + blockIdx.x;
    const int q = (gx * gridDim.y) >> 3;
    wg = (wg & 7) * q + (wg >> 3);
    const int bm = (wg / gx) * 128, bn = (wg % gx) * 128;

    const int wm = (wid >> 1) * 64, wn = (wid & 1) * 64;

    f32x4 acc[4][4] = {};
    const int r_in = lane >> 2;
    const int cch = (lane & 3) * 8;
    const int rbase = wid * 32;

    auto stage = [&](int buf, int k0) {
#pragma unroll
        for (int i = 0; i < 2; ++i) {
            int rloc = rbase + i * 16;
            gl_lds16(A  + (size_t)(bm + rloc + r_in) * lda + k0 + cch, &As[buf][rloc][0]);
            gl_lds16(BT + (size_t)(bn + rloc + r_in) * ldb + k0 + cch, &Bs[buf][rloc][0]);
        }
    };

    const int nt = K / 32;
    stage(0, 0);
    for (int t = 0; t < nt; ++t) {
        int cur = t & 1;
        __syncthreads();
        if (t + 1 < nt) stage(cur ^ 1, (t + 1) * 32);
        bf16x8 af[4], bfr[4];
#pragma unroll
        for (int mi = 0; mi < 4; ++mi)
            af[mi] = *(const bf16x8*)&As[cur][wm + mi * 16 + (lane & 15)][(lane >> 4) * 8];
#pragma unroll
        for (int ni = 0; ni < 4; ++ni)
            bfr[ni] = *(const bf16x8*)&Bs[cur][wn + ni * 16 + (lane & 15)][(lane >> 4) * 8];
#pragma unroll
        for (int mi = 0; mi < 4; ++mi)
#pragma unroll
            for (int ni = 0; ni < 4; ++ni)
                acc[mi][ni] = __builtin_amdgcn_mfma_f32_16x16x32_bf16(
                    af[mi], bfr[ni], acc[mi][ni], 0, 0, 0);
    }

#pragma unroll
    for (int ni = 0; ni < 4; ++ni) {
        int gcol = bn + wn + ni * 16 + (lane & 15);
        float bv = BIAS ? bias[gcol] : 0.f;
#pragma unroll
        for (int mi = 0; mi < 4; ++mi) {
#pragma unroll
            for (int q2 = 0; q2 < 4; ++q2) {
                int grow = bm + wm + mi * 16 + ((lane >> 4) << 2) + q2;
                float x = acc[mi][ni][q2] + bv;
                if (RELU) x = fmaxf(x, 0.f);
                if (OUTBF16)
                    Cb[(size_t)grow * ldc + gcol] = bf16r(x);
                else
                    Cf[(size_t)grow * ldc + gcol] = x;
            }
        }
    }
}

// ---------------------------------------------------------------------------
// Fused GEMM2 + log_softmax + P-gather (R13 v4, verified twice). One block =
// 128 rows x V=512; 16 waves = 2 row-groups x 8 col-groups; LDS 80KB;
// post-loop region reused for reductions + 64-row prob tile (2-phase gather
// into P). lp written IN PLACE over H (block-self-contained rows).
// ---------------------------------------------------------------------------
__global__ __launch_bounds__(1024) void gemm2_lsm(
    const unsigned short* __restrict__ H,     // [65536][1024] bf16 (= d_out)
    const unsigned short* __restrict__ W2T,   // [512][1024] bf16
    const float* __restrict__ b2,             // [512]
    const int* __restrict__ targets,          // [B][256]
    float* __restrict__ lp,                   // [65536][512] f32 (= d_out)
    unsigned short* __restrict__ P)           // [65536][PSTRIDE]
{
    __shared__ __align__(16) char SMEM[81920];
    unsigned short* As = (unsigned short*)SMEM;            // [2][128][32]
    unsigned short* Bs = (unsigned short*)(SMEM + 16384);  // [2][512][32]
    float* redm = (float*)SMEM;                            // [8][128] (post-loop)
    float* reds = (float*)(SMEM + 4096);                   // [8][128]
    unsigned short* prt = (unsigned short*)(SMEM + 8192);  // [64][512] bf16 prob tile
    int* s_tg = (int*)(SMEM + 8192 + 65536);               // [256]

    const int tid = threadIdx.x;
    const int wid = tid >> 6, lane = tid & 63;
    const int wr = wid >> 3, wc = wid & 7;
    const int r0 = blockIdx.x * 128;
    const int b = r0 >> 11;

    auto stage = [&](int buf, int k0) {
#pragma unroll
        for (int ii = 0; ii < 3; ++ii) {
            int issue = wid + 16 * ii;
            if (issue < 8) {
                int rr = issue * 16;
                gl_lds16(H + (size_t)(r0 + rr + (lane >> 2)) * 1024 + k0 + (lane & 3) * 8,
                         &As[buf * 4096 + rr * 32]);
            } else if (issue < 40) {
                int rr = (issue - 8) * 16;
                gl_lds16(W2T + (size_t)(rr + (lane >> 2)) * 1024 + k0 + (lane & 3) * 8,
                         &Bs[buf * 16384 + rr * 32]);
            }
        }
    };

    f32x4 acc[4][4] = {};
    stage(0, 0);
    for (int t = 0; t < 32; ++t) {
        const int cur = t & 1;
        __syncthreads();
        if (t + 1 < 32) stage(cur ^ 1, (t + 1) * 32);
        bf16x8 af[4], bfr[4];
#pragma unroll
        for (int mi = 0; mi < 4; ++mi)
            af[mi] = *(const bf16x8*)&As[cur * 4096 +
                        (wr * 64 + mi * 16 + (lane & 15)) * 32 + (lane >> 4) * 8];
#pragma unroll
        for (int ni = 0; ni < 4; ++ni)
            bfr[ni] = *(const bf16x8*)&Bs[cur * 16384 +
                        (wc * 64 + ni * 16 + (lane & 15)) * 32 + (lane >> 4) * 8];
#pragma unroll
        for (int mi = 0; mi < 4; ++mi)
#pragma unroll
            for (int ni = 0; ni < 4; ++ni)
                acc[mi][ni] = __builtin_amdgcn_mfma_f32_16x16x32_bf16(
                    af[mi], bfr[ni], acc[mi][ni], 0, 0, 0);
    }

    float bcol[4];
#pragma unroll
    for (int ni = 0; ni < 4; ++ni) bcol[ni] = b2[wc * 64 + ni * 16 + (lane & 15)];
#pragma unroll
    for (int mi = 0; mi < 4; ++mi)
#pragma unroll
        for (int ni = 0; ni < 4; ++ni)
#pragma unroll
            for (int q = 0; q < 4; ++q) acc[mi][ni][q] += bcol[ni];

    if (tid < 256) s_tg[tid] = targets[b * L_ + tid];
    __syncthreads();

    float rm[4][4];
#pragma unroll
    for (int mi = 0; mi < 4; ++mi)
#pragma unroll
        for (int q = 0; q < 4; ++q) {
            float m = acc[mi][0][q];
#pragma unroll
            for (int ni = 1; ni < 4; ++ni) m = fmaxf(m, acc[mi][ni][q]);
#pragma unroll
            for (int off = 1; off < 16; off <<= 1) m = fmaxf(m, __shfl_xor(m, off));
            rm[mi][q] = m;
        }
    if ((lane & 15) == 0) {
#pragma unroll
        for (int mi = 0; mi < 4; ++mi)
#pragma unroll
            for (int q = 0; q < 4; ++q)
                redm[wc * 128 + wr * 64 + mi * 16 + ((lane >> 4) << 2) + q] = rm[mi][q];
    }
    __syncthreads();
#pragma unroll
    for (int mi = 0; mi < 4; ++mi)
#pragma unroll
        for (int q = 0; q < 4; ++q) {
            int row = wr * 64 + mi * 16 + ((lane >> 4) << 2) + q;
            float m = redm[row];
#pragma unroll
            for (int g = 1; g < 8; ++g) m = fmaxf(m, redm[g * 128 + row]);
            rm[mi][q] = m;
        }
    float rs[4][4];
#pragma unroll
    for (int mi = 0; mi < 4; ++mi)
#pragma unroll
        for (int q = 0; q < 4; ++q) {
            float s = 0.f;
#pragma unroll
            for (int ni = 0; ni < 4; ++ni) s += expf(acc[mi][ni][q] - rm[mi][q]);
#pragma unroll
            for (int off = 1; off < 16; off <<= 1) s += __shfl_xor(s, off);
            rs[mi][q] = s;
        }
    if ((lane & 15) == 0) {
#pragma unroll
        for (int mi = 0; mi < 4; ++mi)
#pragma unroll
            for (int q = 0; q < 4; ++q)
                reds[wc * 128 + wr * 64 + mi * 16 + ((lane >> 4) << 2) + q] = rs[mi][q];
    }
    __syncthreads();
#pragma unroll
    for (int mi = 0; mi < 4; ++mi)
#pragma unroll
        for (int q = 0; q < 4; ++q) {
            int row = wr * 64 + mi * 16 + ((lane >> 4) << 2) + q;
            float st = reds[row];
#pragma unroll
            for (int g = 1; g < 8; ++g) st += reds[g * 128 + row];
            rm[mi][q] = rm[mi][q] + logf(st);   // lse
        }

#pragma unroll
    for (int p = 0; p < 2; ++p) {
        if (wr == p) {
#pragma unroll
            for (int mi = 0; mi < 4; ++mi)
#pragma unroll
                for (int q = 0; q < 4; ++q) {
                    int rloc = mi * 16 + ((lane >> 4) << 2) + q;
                    int row = wr * 64 + rloc;
#pragma unroll
                    for (int ni = 0; ni < 4; ++ni) {
                        int col = wc * 64 + ni * 16 + (lane & 15);
                        float lpv = acc[mi][ni][q] - rm[mi][q];
                        lp[(size_t)(r0 + row) * 512 + col] = lpv;
                        prt[rloc * 512 + col] = bf16r(expf(lpv) * BOOST);
                    }
                }
        }
        __syncthreads();
        if (tid < 514) {
            int j = tid % 257;
            int rh = tid / 257;
            int col = (j < 256) ? s_tg[j] : BLANKI;
#pragma unroll 4
            for (int r = rh * 32; r < rh * 32 + 32; ++r)
                P[(size_t)(r0 + p * 64 + r) * PSTRIDE + j] = prt[r * 512 + col];
        }
        __syncthreads();
    }
}

// ---------------------------------------------------------------------------
// CTC forward/backward DP split, f64, depth-16 NAMED-register pipeline
// (R12 structure, measured 149us: 64 blocks x 1 wave, per-step issue-bound
// ~350cyc — R15 proved dual-chain-per-wave is additive, R13 proved wave
// packing contends; this split is the measured floor for the structure).
// ---------------------------------------------------------------------------
struct Pr5 { float pb, p1, p3, p5, p7; };

__device__ __forceinline__ Pr5 ldrowf(const unsigned short* rp, int l)
{
    ushort4 q = *(const ushort4*)(rp + 4 * l);
    Pr5 r;
    r.pb = bf2f(rp[256]);
    r.p1 = bf2f(q.x); r.p3 = bf2f(q.y); r.p5 = bf2f(q.z); r.p7 = bf2f(q.w);
    return r;
}

#define REP16(OP) OP(0) OP(1) OP(2) OP(3) OP(4) OP(5) OP(6) OP(7) \
                  OP(8) OP(9) OP(10) OP(11) OP(12) OP(13) OP(14) OP(15)

__global__ __launch_bounds__(64) void ctc_fwd_bwd(
    const unsigned short* __restrict__ P,
    const int* __restrict__ enc_mask, const int* __restrict__ targets,
    const int* __restrict__ tgt_mask,
    float* __restrict__ out_len_f,
    double* __restrict__ AV, double* __restrict__ BV,
    int* __restrict__ EF, int* __restrict__ EB,
    int* __restrict__ ILv, int* __restrict__ tl_out)
{
    const int b = blockIdx.x & 31;
    const bool isf = blockIdx.x < 32;
    const int l = threadIdx.x;

    int se = 0, st = 0;
    {
        const int* em = enc_mask + (size_t)b * SSRC;
#pragma unroll
        for (int i = 0; i < 8; ++i) se += (em[i * 64 + l] != 0) ? 1 : 0;
        const int* tm = tgt_mask + (size_t)b * L_;
#pragma unroll
        for (int i = 0; i < 4; ++i) st += (tm[i * 64 + l] != 0) ? 1 : 0;
#pragma unroll
        for (int off = 32; off; off >>= 1) {
            se += __shfl_xor(se, off);
            st += __shfl_xor(st, off);
        }
    }
    const int tl = st;
    const int IL = STRIDE_ * se;
    const int h = (IL > 0) ? ((IL - 1) >> 1) : 0;

    const int4 tg = ((const int4*)(targets + (size_t)b * L_))[l];
    int prevw = __shfl_up(tg.w, 1);
    if (l == 0) prevw = BLANKI;
    const bool k1 = (tg.x != BLANKI) && (tg.x != prevw);
    const bool k3 = (tg.y != BLANKI) && (tg.y != tg.x);
    const bool k5 = (tg.z != BLANKI) && (tg.z != tg.y);
    const bool k7 = (tg.w != BLANKI) && (tg.w != tg.z);

    const unsigned short* Pb = P + (size_t)b * T_ * PSTRIDE;

    double a0 = 0, a1 = 0, a2 = 0, a3 = 0, a4 = 0, a5 = 0, a6 = 0, a7 = 0, a8 = 0;
    int Ei = 0;

    auto rescale9 = [&]() {
        double m = fmax(fmax(fmax(a0, a1), fmax(a2, a3)),
                        fmax(fmax(a4, a5), fmax(fmax(a6, a7), a8)));
        int e = (int)((__double_as_longlong(m) >> 52) & 0x7ff);
#pragma unroll
        for (int off = 1; off < 64; off <<= 1) {
            int o = __shfl_xor(e, off);
            e = o > e ? o : e;
        }
        int sh = 1023 - e;
        double sc = __longlong_as_double(((long long)(sh + 1023)) << 52);
        Ei += e - 1023;
        a0 *= sc; a1 *= sc; a2 *= sc; a3 *= sc; a4 *= sc;
        a5 *= sc; a6 *= sc; a7 *= sc; a8 *= sc;
    };

    if (isf) {
        if (l == 0) {
            a0 = (double)bf2f(Pb[256]);
            if (tl > 0) a1 = (double)bf2f(Pb[0]);
        }
        auto fstep = [&](const Pr5& r) {
            double pb = (double)r.pb, p1 = (double)r.p1, p3 = (double)r.p3;
            double p5 = (double)r.p5, p7 = (double)r.p7;
            double u1 = __shfl_up(a7, 1);
            if (l == 0) u1 = 0.0;
            double n0 = (a0 + u1) * pb;
            double n1 = (a0 + a1 + (k1 ? u1 : 0.0)) * p1;
            double n2 = (a1 + a2) * pb;
            double n3 = (a2 + a3 + (k3 ? a1 : 0.0)) * p3;
            double n4 = (a3 + a4) * pb;
            double n5 = (a4 + a5 + (k5 ? a3 : 0.0)) * p5;
            double n6 = (a5 + a6) * pb;
            double n7 = (a6 + a7 + (k7 ? a5 : 0.0)) * p7;
            double n8 = (l == 63) ? (a7 + a8) * pb : 0.0;
            a0 = n0; a1 = n1; a2 = n2; a3 = n3; a4 = n4;
            a5 = n5; a6 = n6; a7 = n7; a8 = n8;
        };
        const int nst = h;
        if (nst > 0) {
            Pr5 q0, q1, q2, q3, q4, q5, q6, q7, q8, q9, q10, q11, q12, q13, q14, q15;
#define LDI(i) { int ti = 1 + i; if (ti > nst) ti = nst; \
                 q##i = ldrowf(Pb + (size_t)ti * PSTRIDE, l); }
            REP16(LDI)
#undef LDI
            int t = 1;
            while (t + 15 <= nst) {
#define STP(i) { fstep(q##i); int ti = t + 16 + i; if (ti > nst) ti = nst; \
                 q##i = ldrowf(Pb + (size_t)ti * PSTRIDE, l); }
                REP16(STP)
#undef STP
                rescale9();
                t += 16;
            }
            int rem = nst - t + 1;
#define TLS(i) if (i < rem) fstep(q##i);
            REP16(TLS)
#undef TLS
        }
        rescale9();
        double* av = AV + b * 520;
        av[l * 8 + 0] = a0; av[l * 8 + 1] = a1; av[l * 8 + 2] = a2; av[l * 8 + 3] = a3;
        av[l * 8 + 4] = a4; av[l * 8 + 5] = a5; av[l * 8 + 6] = a6; av[l * 8 + 7] = a7;
        if (l == 63) av[512] = a8;
        if (l == 0) {
            EF[b] = Ei; ILv[b] = IL; tl_out[b] = tl;
            out_len_f[b] = (float)IL;
        }
    } else {
        {
            int s0 = l * 8;
            int e0 = 2 * tl, e1 = 2 * tl - 1;
            a0 = (s0 + 0 == e0 || (tl > 0 && s0 + 0 == e1)) ? 1.0 : 0.0;
            a1 = (s0 + 1 == e0 || (tl > 0 && s0 + 1 == e1)) ? 1.0 : 0.0;
            a2 = (s0 + 2 == e0 || (tl > 0 && s0 + 2 == e1)) ? 1.0 : 0.0;
            a3 = (s0 + 3 == e0 || (tl > 0 && s0 + 3 == e1)) ? 1.0 : 0.0;
            a4 = (s0 + 4 == e0 || (tl > 0 && s0 + 4 == e1)) ? 1.0 : 0.0;
            a5 = (s0 + 5 == e0 || (tl > 0 && s0 + 5 == e1)) ? 1.0 : 0.0;
            a6 = (s0 + 6 == e0 || (tl > 0 && s0 + 6 == e1)) ? 1.0 : 0.0;
            a7 = (s0 + 7 == e0 || (tl > 0 && s0 + 7 == e1)) ? 1.0 : 0.0;
            if (l == 63) a8 = (512 == e0) ? 1.0 : 0.0;
        }
        float knff = __shfl_down(k1 ? 1.f : 0.f, 1);
        if (l == 63) knff = 0.f;
        const double knf = (double)knff;
        auto bstep = [&](const Pr5& r) {
            double pb = (double)r.pb, p1 = (double)r.p1, p3 = (double)r.p3;
            double p5 = (double)r.p5, p7 = (double)r.p7;
            double g0 = a0 * pb, g1 = a1 * p1, g2 = a2 * pb, g3 = a3 * p3;
            double g4 = a4 * pb, g5 = a5 * p5, g6 = a6 * pb, g7 = a7 * p7;
            double g8 = (l == 63) ? a8 * pb : 0.0;
            double d1 = __shfl_down(g0, 1);
            double d2 = __shfl_down(g1, 1);
            if (l == 63) { d1 = g8; d2 = 0.0; }
            double m0 = g0 + g1;
            double m1 = g1 + g2 + (k3 ? g3 : 0.0);
            double m2 = g2 + g3;
            double m3 = g3 + g4 + (k5 ? g5 : 0.0);
            double m4 = g4 + g5;
            double m5 = g5 + g6 + (k7 ? g7 : 0.0);
            double m6 = g6 + g7;
            double m7 = g7 + d1 + knf * d2;
            double m8 = (l == 63) ? g8 : 0.0;
            a0 = m0; a1 = m1; a2 = m2; a3 = m3; a4 = m4;
            a5 = m5; a6 = m6; a7 = m7; a8 = m8;
        };
        const int nbs = IL - 1 - h;
        if (nbs > 0) {
            const int rmin = h + 1;
            Pr5 q0, q1, q2, q3, q4, q5, q6, q7, q8, q9, q10, q11, q12, q13, q14, q15;
#define LDB(i) { int ri = IL - 1 - i; if (ri < rmin) ri = rmin; \
                 q##i = ldrowf(Pb + (size_t)ri * PSTRIDE, l); }
            REP16(LDB)
#undef LDB
            int j = 0;
            while (j + 16 <= nbs) {
#define STB(i) { bstep(q##i); int ri = IL - 1 - (j + 16 + i); if (ri < rmin) ri = rmin; \
                 q##i = ldrowf(Pb + (size_t)ri * PSTRIDE, l); }
                REP16(STB)
#undef STB
                rescale9();
                j += 16;
            }
            int rem = nbs - j;
#define TLB(i) if (i < rem) bstep(q##i);
            REP16(TLB)
#undef TLB
        }
        rescale9();
        double* bv = BV + b * 520;
        bv[l * 8 + 0] = a0; bv[l * 8 + 1] = a1; bv[l * 8 + 2] = a2; bv[l * 8 + 3] = a3;
        bv[l * 8 + 4] = a4; bv[l * 8 + 5] = a5; bv[l * 8 + 6] = a6; bv[l * 8 + 7] = a7;
        if (l == 63) bv[512] = a8;
        if (l == 0) EB[b] = Ei;
    }
}

// ---------------------------------------------------------------------------
__global__ __launch_bounds__(64) void ctc_combine(
    const double* __restrict__ AV, const double* __restrict__ BV,
    const int* __restrict__ EF, const int* __restrict__ EB,
    const int* __restrict__ ILv, float* __restrict__ per_sample)
{
    const int b = blockIdx.x, l = threadIdx.x;
    const double* av = AV + b * 520;
    const double* bv = BV + b * 520;
    double s = 0.0;
#pragma unroll
    for (int i = 0; i < 8; ++i)
        s += av[l * 8 + i] * bv[l * 8 + i];
    if (l == 63) s += av[512] * bv[512];
#pragma unroll
    for (int off = 1; off < 64; off <<= 1) s += __shfl_xor(s, off);
    if (l == 0) {
        double lg = log(s) +
            (double)(EF[b] + EB[b] - BOOST_BITS * ILv[b]) * 0.6931471805599453;
        per_sample[b] = -(float)lg;
    }
}

__global__ __launch_bounds__(64) void ctc_loss_final(
    const float* __restrict__ per_sample, const int* __restrict__ tl,
    float* __restrict__ out_loss)
{
    int tid = threadIdx.x;
    float v = 0.f;
    if (tid < B_) {
        int t = tl[tid] < 1 ? 1 : tl[tid];
        v = per_sample[tid] / (float)t;
    }
#pragma unroll
    for (int off = 32; off; off >>= 1) v += __shfl_down(v, off);
    if (tid == 0) {
        float loss = v / (float)B_;
        if (isnan(loss) || isinf(loss)) loss = 0.f;
        *out_loss = loss;
    }
}

// ---------------------------------------------------------------------------
extern "C" void kernel_launch(void* const* d_in, const int* in_sizes, int n_in,
                              void* d_out, int out_size, void* d_ws, size_t ws_size,
                              hipStream_t stream)
{
    (void)in_sizes; (void)n_in; (void)out_size; (void)ws_size;

    const float* rep      = (const float*)d_in[0];
    const int*   enc_mask = (const int*)d_in[1];
    const int*   targets  = (const int*)d_in[2];
    const int*   tgt_mask = (const int*)d_in[3];
    const float* W_exp    = (const float*)d_in[4];
    const float* b_exp    = (const float*)d_in[5];
    const float* W1       = (const float*)d_in[6];
    const float* b1       = (const float*)d_in[7];
    const float* W2       = (const float*)d_in[8];
    const float* b2       = (const float*)d_in[9];

    float* out       = (float*)d_out;
    float* logprobs  = out;                          // [65536][512] f32
    float* out_len_f = out + (size_t)B_ * T_ * V_;
    float* out_loss  = out_len_f + B_;
    unsigned short* Hd = (unsigned short*)d_out;     // H bf16 [65536][1024] (same bytes)

    // ws layout (~39.1 MB):
    unsigned short* WcT = (unsigned short*)d_ws;                  // [4096][512] bf16, 4 MB
    float* bc           = (float*)(WcT + (size_t)4096 * 512);     // [4096]
    float* per_sample   = bc + 4096;                              // [64]
    int*   tl_out       = (int*)(per_sample + 64);                // [64]
    unsigned short* P   = (unsigned short*)(tl_out + 64);         // [65536][264], 34.6 MB
    double* AV          = (double*)(P + (size_t)65536 * PSTRIDE); // [32][520] f64
    double* BV          = AV + 32 * 520;                          // [32][520] f64
    int*   EF           = (int*)(BV + 32 * 520);                  // [32]
    int*   EB           = EF + 32;                                // [32]
    int*   ILv          = EB + 32;                                // [32]
    // aliased inside P (all dead before gemm2_lsm writes P):
    unsigned short* repb   = P;                                   // [16384][512]
    unsigned short* W_expb = P + (size_t)16384 * 512;             // [512][2048]
    unsigned short* W1T    = W_expb + (size_t)512 * 2048;         // [1024][512]
    unsigned short* W2T    = WcT;                                 // [512][1024] (after gemm1)

    // 1) conversions
    cvt_f32_bf16<<<8192, 256, 0, stream>>>(rep, repb, (16384 * 512) / 4);
    cvt_f32_bf16<<<1024, 256, 0, stream>>>(W_exp, W_expb, (512 * 2048) / 4);
    transpose_cvt<<<dim3(32, 16), dim3(32, 8), 0, stream>>>(W1, W1T, 512, 1024);

    // 2) fold via MFMA: WcT[(k*1024+h)][e] = sum_d W1T[h][d] * W_exp[e][k*512+d]
    gemm_mfma<false, true, false><<<dim3(4, 8, 4), 256, 0, stream>>>(
        W1T, 512, 0, W_expb, 2048, 512, WcT, 512, (long)1024 * 512, nullptr, 512);
    combine_bias<<<16, 256, 0, stream>>>(b_exp, W1, b1, bc);

    // 3) GEMM1 (single launch): H = relu(rep @ Wc + bc) bf16 -> d_out
    gemm_mfma<true, true, true><<<dim3(32, 128), 256, 0, stream>>>(
        repb, 512, 0, WcT, 512, 0, Hd, 4096, 0, bc, 512);

    // 4) W2 -> W2T (into the now-dead WcT region)
    transpose_cvt<<<dim3(16, 32), dim3(32, 8), 0, stream>>>(W2, W2T, 1024, 512);

    // 5) fused GEMM2 + log_softmax + gather (in-place lp over H; writes P)
    gemm2_lsm<<<512, 1024, 0, stream>>>(Hd, W2T, b2, targets, logprobs, P);

    // 6) CTC DP: fwd (blocks 0-31) + bwd (blocks 32-63), combine, loss
    ctc_fwd_bwd<<<64, 64, 0, stream>>>(P, enc_mask, targets, tgt_mask,
                                       out_len_f, AV, BV, EF, EB, ILv, tl_out);
    ctc_combine<<<32, 64, 0, stream>>>(AV, BV, EF, EB, ILv, per_sample);
    ctc_loss_final<<<1, 64, 0, stream>>>(per_sample, tl_out, out_loss);
}